// Round 3
// baseline (403.028 us; speedup 1.0000x reference)
//
#include <hip/hip_runtime.h>
#include <stdint.h>

#define D_MODEL 4096
#define N_EXP   64
#define N_TOK   16384
#define MTILE   64
#define KC      64
#define NCHUNK  (D_MODEL / KC)

typedef float  f32x4  __attribute__((ext_vector_type(4)));
typedef short  bf16x8 __attribute__((ext_vector_type(8)));

// Split one fp32 into bf16 hi (RNE) + bf16 lo (truncated residual).
// Packs 8 floats -> 8 bf16 hi (uint4) + 8 bf16 lo (uint4).
__device__ __forceinline__ void cvt8(float4 v0, float4 v1, uint4& hp, uint4& lp) {
  float f[8] = {v0.x, v0.y, v0.z, v0.w, v1.x, v1.y, v1.z, v1.w};
  unsigned hb[8], lb[8];
#pragma unroll
  for (int i = 0; i < 8; ++i) {
    unsigned u = __builtin_bit_cast(unsigned, f[i]);
    unsigned r = u + 0x7FFFu + ((u >> 16) & 1u);   // RNE to bf16
    unsigned h = r & 0xFFFF0000u;                  // hi as f32 bits
    float    res = f[i] - __builtin_bit_cast(float, h);  // exact (Sterbenz)
    lb[i] = __builtin_bit_cast(unsigned, res);     // lo = truncate(res)
    hb[i] = h;
  }
  hp.x = (hb[0] >> 16) | hb[1];
  hp.y = (hb[2] >> 16) | hb[3];
  hp.z = (hb[4] >> 16) | hb[5];
  hp.w = (hb[6] >> 16) | hb[7];
  lp.x = (lb[0] >> 16) | (lb[1] & 0xFFFF0000u);
  lp.y = (lb[2] >> 16) | (lb[3] & 0xFFFF0000u);
  lp.z = (lb[4] >> 16) | (lb[5] & 0xFFFF0000u);
  lp.w = (lb[6] >> 16) | (lb[7] & 0xFFFF0000u);
}

// XOR-swizzled 16B-slot address within a [64][KC] bf16 LDS tile (G4 fix for
// the stride-128B bank conflict on ds_read_b128 fragment reads).
__device__ __forceinline__ void* lds_slot(void* buf, int row, int kb) {
  return (void*)((char*)buf + ((((row) << 3) + ((kb) ^ ((row) & 7))) << 4));
}

__global__ __launch_bounds__(256) void SimpleMoERouter_54219667144993_kernel(
    const float* __restrict__ X, const float* __restrict__ W,
    float* __restrict__ outw, float* __restrict__ outi)
{
  __shared__ short sAh[MTILE * KC];
  __shared__ short sAl[MTILE * KC];
  __shared__ short sWh[N_EXP * KC];
  __shared__ short sWl[N_EXP * KC];
  __shared__ float sLog[MTILE * 65];   // +1-pad rows

  const int tid  = threadIdx.x;
  const int lane = tid & 63;
  const int wv   = tid >> 6;
  const int tok0 = blockIdx.x * MTILE;

  // staging map: thread -> (row = tid>>3 in 0..31, kblock = tid&7 -> 8 floats)
  const int srow = tid >> 3;
  const int skb  = tid & 7;

  const float* gA0 = X + (size_t)(tok0 + srow) * D_MODEL + skb * 8;
  const float* gA1 = gA0 + (size_t)32 * D_MODEL;
  const float* gW0 = W + (size_t)srow * D_MODEL + skb * 8;
  const float* gW1 = gW0 + (size_t)32 * D_MODEL;

  float4 st[8];

  auto LOAD = [&](int it) {
    const int off = it * KC;
    st[0] = *(const float4*)(gA0 + off);
    st[1] = *(const float4*)(gA0 + off + 4);
    st[2] = *(const float4*)(gA1 + off);
    st[3] = *(const float4*)(gA1 + off + 4);
    st[4] = *(const float4*)(gW0 + off);
    st[5] = *(const float4*)(gW0 + off + 4);
    st[6] = *(const float4*)(gW1 + off);
    st[7] = *(const float4*)(gW1 + off + 4);
  };

  auto STORE = [&]() {
    uint4 hp, lp;
    cvt8(st[0], st[1], hp, lp);
    *(uint4*)lds_slot(sAh, srow, skb) = hp;
    *(uint4*)lds_slot(sAl, srow, skb) = lp;
    cvt8(st[2], st[3], hp, lp);
    *(uint4*)lds_slot(sAh, srow + 32, skb) = hp;
    *(uint4*)lds_slot(sAl, srow + 32, skb) = lp;
    cvt8(st[4], st[5], hp, lp);
    *(uint4*)lds_slot(sWh, srow, skb) = hp;
    *(uint4*)lds_slot(sWl, srow, skb) = lp;
    cvt8(st[6], st[7], hp, lp);
    *(uint4*)lds_slot(sWh, srow + 32, skb) = hp;
    *(uint4*)lds_slot(sWl, srow + 32, skb) = lp;
  };

  f32x4 acc[4] = {{0.f,0.f,0.f,0.f},{0.f,0.f,0.f,0.f},
                  {0.f,0.f,0.f,0.f},{0.f,0.f,0.f,0.f}};

  // MFMA fragment addressing: A[m][k] lane m=l&15, k=(l>>4)*8+j (contiguous 8)
  const int arow = wv * 16 + (lane & 15);
  const int kq   = lane >> 4;

  LOAD(0);
  STORE();
  __syncthreads();

  for (int it = 0; it < NCHUNK; ++it) {
    if (it + 1 < NCHUNK) LOAD(it + 1);   // issue next chunk early (T14)
#pragma unroll
    for (int h = 0; h < 2; ++h) {
      const int kb = h * 4 + kq;
      bf16x8 ah = *(const bf16x8*)lds_slot(sAh, arow, kb);
      bf16x8 al = *(const bf16x8*)lds_slot(sAl, arow, kb);
#pragma unroll
      for (int nt = 0; nt < 4; ++nt) {
        const int brow = nt * 16 + (lane & 15);
        bf16x8 bh = *(const bf16x8*)lds_slot(sWh, brow, kb);
        bf16x8 bl = *(const bf16x8*)lds_slot(sWl, brow, kb);
        acc[nt] = __builtin_amdgcn_mfma_f32_16x16x32_bf16(ah, bh, acc[nt], 0, 0, 0);
        acc[nt] = __builtin_amdgcn_mfma_f32_16x16x32_bf16(ah, bl, acc[nt], 0, 0, 0);
        acc[nt] = __builtin_amdgcn_mfma_f32_16x16x32_bf16(al, bh, acc[nt], 0, 0, 0);
      }
    }
    __syncthreads();
    if (it + 1 < NCHUNK) {
      STORE();               // regs -> LDS for chunk it+1
      __syncthreads();
    }
  }

  // Scatter accumulators into logits LDS: C/D layout col=lane&15 (expert),
  // row=(lane>>4)*4+reg (token)  [verified m89/m91]
#pragma unroll
  for (int nt = 0; nt < 4; ++nt) {
#pragma unroll
    for (int r = 0; r < 4; ++r) {
      const int trow = wv * 16 + (lane >> 4) * 4 + r;
      const int e    = nt * 16 + (lane & 15);
      sLog[trow * 65 + e] = acc[nt][r];
    }
  }
  __syncthreads();

  // Top-2 + softmax: one thread per token (tiny vs GEMM cost)
  if (tid < MTILE) {
    float best = -3.4e38f, sec = -3.4e38f;
    int bi = 0, si = 0;
#pragma unroll 8
    for (int e = 0; e < N_EXP; ++e) {
      const float v  = sLog[tid * 65 + e];
      const bool b1 = v > best;   // strict > keeps earliest index on ties (lax.top_k)
      const bool b2 = v > sec;
      sec  = b1 ? best : (b2 ? v : sec);
      si   = b1 ? bi   : (b2 ? e : si);
      best = b1 ? v : best;
      bi   = b1 ? e : bi;
    }
    const float ed  = expf(sec - best);
    const float inv = 1.0f / (1.0f + ed);
    const int gt = tok0 + tid;
    outw[2 * gt]     = inv;        // softmax of [best, sec]
    outw[2 * gt + 1] = ed * inv;
    // Harness reads the whole d_out as float32 — indices must be stored as
    // float VALUES, not int bits (R1 failure: absmax 63 == max index).
    outi[2 * gt]     = (float)bi;
    outi[2 * gt + 1] = (float)si;
  }
}

extern "C" void kernel_launch(void* const* d_in, const int* in_sizes, int n_in,
                              void* d_out, int out_size, void* d_ws, size_t ws_size,
                              hipStream_t stream) {
  const float* X = (const float*)d_in[0];
  const float* W = (const float*)d_in[1];
  float* outw = (float*)d_out;
  float* outi = (float*)d_out + (size_t)N_TOK * 2;   // indices follow weights, as f32 values
  hipLaunchKernelGGL(SimpleMoERouter_54219667144993_kernel,
                     dim3(N_TOK / MTILE), dim3(256), 0, stream,
                     X, W, outw, outi);
}